// Round 3
// baseline (1260.396 us; speedup 1.0000x reference)
//
#include <hip/hip_runtime.h>
#include <stdint.h>

typedef uint32_t u32;
typedef uint64_t u64;
typedef uint8_t  u8;

#define KEY_MIN   0x3C000000u   /* conf = max softmax >= 1/C = 0.01 > 2^-7 */
#define SUBSHIFT  10
#define NBUCK     57344         /* (0x3F800000 - 0x3C000000) >> 10 */
#define NBINS     20
#define NB        19
#define TBLK      1024          /* tail grid blocks (4/CU, co-resident) */
#define TTHR      256
#define CHUNK     (NBUCK / TBLK)  /* 56 */

__device__ __forceinline__ u32 bucket_of(u32 key) {
    if (key < KEY_MIN) return 0u;
    u32 b = (key - KEY_MIN) >> SUBSHIFT;
    return b < (u32)NBUCK ? b : (u32)(NBUCK - 1);
}

// ---------------- K1 (C==100): 16 lanes per row, coalesced --------------------
__global__ __launch_bounds__(256) void k1_conf100(
        const float* __restrict__ logits, const int* __restrict__ labels,
        u32* __restrict__ keys, u8* __restrict__ accb, u32* __restrict__ hist,
        int N) {
    const int C4 = 25;
    int lane = threadIdx.x & 63;
    int wid  = (blockIdx.x * (blockDim.x >> 6)) + (threadIdx.x >> 6);
    int g    = lane >> 4;
    int sub  = lane & 15;
    int r    = wid * 4 + g;
    if (r >= N) return;

    const float4* row4 = (const float4*)(logits + (size_t)r * 100);
    float4 v0 = row4[sub];
    float4 v1;
    bool has2 = (sub + 16) < C4;
    if (has2) v1 = row4[sub + 16];
    else      v1 = make_float4(-3.4e38f, -3.4e38f, -3.4e38f, -3.4e38f);

    float m = v0.x; int am = 4 * sub;
    if (v0.y > m) { m = v0.y; am = 4 * sub + 1; }
    if (v0.z > m) { m = v0.z; am = 4 * sub + 2; }
    if (v0.w > m) { m = v0.w; am = 4 * sub + 3; }
    int b2 = 64 + 4 * sub;
    if (v1.x > m) { m = v1.x; am = b2; }
    if (v1.y > m) { m = v1.y; am = b2 + 1; }
    if (v1.z > m) { m = v1.z; am = b2 + 2; }
    if (v1.w > m) { m = v1.w; am = b2 + 3; }

    #pragma unroll
    for (int off = 8; off >= 1; off >>= 1) {
        float om = __shfl_xor(m, off);
        int   oa = __shfl_xor(am, off);
        if (om > m || (om == m && oa < am)) { m = om; am = oa; }
    }

    float s = __expf(v0.x - m) + __expf(v0.y - m) + __expf(v0.z - m) + __expf(v0.w - m);
    if (has2) s += __expf(v1.x - m) + __expf(v1.y - m) + __expf(v1.z - m) + __expf(v1.w - m);
    #pragma unroll
    for (int off = 8; off >= 1; off >>= 1) s += __shfl_xor(s, off);

    if (sub == 0) {
        float conf = 1.0f / s;
        u32 key = __float_as_uint(conf);
        keys[r] = key;
        accb[r] = (labels[r] == am) ? (u8)1 : (u8)0;
        atomicAdd(&hist[bucket_of(key)], 1u);
    }
}

// ---------------- K1 generic fallback -----------------------------------------
__global__ __launch_bounds__(256) void k1_generic(
        const float* __restrict__ logits, const int* __restrict__ labels,
        u32* __restrict__ keys, u8* __restrict__ accb, u32* __restrict__ hist,
        int N, int C) {
    int i = blockIdx.x * blockDim.x + threadIdx.x;
    if (i >= N) return;
    const float* row = logits + (size_t)i * (size_t)C;
    float m = -3.4e38f, s = 0.f;
    int am = 0;
    for (int c = 0; c < C; c++) {
        float v = row[c];
        float nm = fmaxf(m, v); am = (v > m) ? c : am;
        s = s * __expf(m - nm) + __expf(v - nm); m = nm;
    }
    float conf = 1.0f / s;
    u32 key = __float_as_uint(conf);
    keys[i] = key;
    accb[i] = (labels[i] == am) ? (u8)1 : (u8)0;
    atomicAdd(&hist[bucket_of(key)], 1u);
}

// ---------------- device-scope helpers ----------------------------------------
__device__ __forceinline__ u32 aload(const u32* p) {
    return __hip_atomic_load(p, __ATOMIC_RELAXED, __HIP_MEMORY_SCOPE_AGENT);
}
__device__ __forceinline__ void astore(u32* p, u32 v) {
    __hip_atomic_store(p, v, __ATOMIC_RELAXED, __HIP_MEMORY_SCOPE_AGENT);
}
__device__ __forceinline__ u64 aload64(const u64* p) {
    return __hip_atomic_load(p, __ATOMIC_RELAXED, __HIP_MEMORY_SCOPE_AGENT);
}

__device__ void grid_barrier(u32* cnt, u32* gen) {
    __threadfence();          // release our writes to device scope
    __syncthreads();
    if (threadIdx.x == 0) {
        u32 g = __hip_atomic_load(gen, __ATOMIC_RELAXED, __HIP_MEMORY_SCOPE_AGENT);
        u32 arrived = __hip_atomic_fetch_add(cnt, 1u, __ATOMIC_ACQ_REL, __HIP_MEMORY_SCOPE_AGENT);
        if (arrived == TBLK - 1) {
            __hip_atomic_store(cnt, 0u, __ATOMIC_RELAXED, __HIP_MEMORY_SCOPE_AGENT);
            __hip_atomic_fetch_add(gen, 1u, __ATOMIC_RELEASE, __HIP_MEMORY_SCOPE_AGENT);
        } else {
            while (__hip_atomic_load(gen, __ATOMIC_ACQUIRE, __HIP_MEMORY_SCOPE_AGENT) == g) {
                __builtin_amdgcn_s_sleep(2);
            }
        }
    }
    __syncthreads();
    __threadfence();          // acquire: invalidate stale cached lines
}

// ---------------- TAIL: everything after K1 in one cooperative kernel ---------
// meta: 0..18 bBucket | 19..37 bOff | 38..56 Kkey
__global__ __launch_bounds__(TTHR, 4) void tail_kernel(
        const u32* __restrict__ keys, const u8* __restrict__ accb,
        const u32* __restrict__ hist, u32* __restrict__ subhist,
        u32* __restrict__ meta, u32* __restrict__ partial, u32* __restrict__ chunk_excl,
        u64* __restrict__ confQ, u32* __restrict__ accCnt, u32* __restrict__ bar,
        float* __restrict__ out, int N, u32 W) {
    int bid = blockIdx.x, tid = threadIdx.x;
    u32* cnt = bar; u32* gen = bar + 1;
    __shared__ u32 sh[TTHR];
    __shared__ unsigned long long lc[4][NBINS];
    __shared__ u32 la[4][NBINS];
    __shared__ u32 sK[NB];

    // ---- A1: per-chunk sums of hist (hist written by K1: kernel boundary = safe)
    u32 s = (tid < CHUNK) ? hist[bid * CHUNK + tid] : 0u;
    sh[tid] = s; __syncthreads();
    for (int d = 128; d >= 1; d >>= 1) { if (tid < d) sh[tid] += sh[tid + d]; __syncthreads(); }
    if (tid == 0) astore(&partial[bid], sh[0]);
    grid_barrier(cnt, gen);

    // ---- A2: block 0 exclusive-scans partial[TBLK] -> chunk_excl
    if (bid == 0) {
        u32 v[4];
        #pragma unroll
        for (int k = 0; k < 4; k++) v[k] = aload(&partial[tid * 4 + k]);
        u32 tsum = v[0] + v[1] + v[2] + v[3];
        sh[tid] = tsum; __syncthreads();
        for (int d = 1; d < TTHR; d <<= 1) {
            u32 x = (tid >= d) ? sh[tid - d] : 0u;
            __syncthreads(); sh[tid] += x; __syncthreads();
        }
        u32 run = sh[tid] - tsum;
        #pragma unroll
        for (int k = 0; k < 4; k++) { astore(&chunk_excl[tid * 4 + k], run); run += v[k]; }
    }
    grid_barrier(cnt, gen);

    // ---- A3: locate boundary buckets (serial 56-walk per block, thread 0)
    if (tid == 0) {
        u32 cum = aload(&chunk_excl[bid]);
        for (int k = 0; k < CHUNK; k++) {
            u32 c = hist[bid * CHUNK + k];
            if (c) {
                for (int j = 0; j < NB; j++) {
                    u32 r = (u32)(j + 1) * W;
                    if (cum < r && r <= cum + c) {
                        astore(&meta[j], (u32)(bid * CHUNK + k));
                        astore(&meta[NB + j], r - cum);
                    }
                }
            }
            cum += c;
        }
    }
    grid_barrier(cnt, gen);

    // ---- B: sub-histogram (low 10 bits) of boundary buckets
    if (tid < NB) sK[tid] = aload(&meta[tid]);
    __syncthreads();
    {
        int total4 = N >> 2;
        const uint4* k4 = (const uint4*)keys;
        for (int i = bid * TTHR + tid; i < total4; i += TBLK * TTHR) {
            uint4 kv = k4[i];
            u32 ks[4] = {kv.x, kv.y, kv.z, kv.w};
            #pragma unroll
            for (int e = 0; e < 4; e++) {
                u32 b = bucket_of(ks[e]);
                #pragma unroll
                for (int j = 0; j < NB; j++)
                    if (b == sK[j]) atomicAdd(&subhist[j * 1024 + (ks[e] & 1023u)], 1u);
            }
        }
        for (int i = (total4 << 2) + bid * TTHR + tid; i < N; i += TBLK * TTHR) {
            u32 k = keys[i];
            u32 b = bucket_of(k);
            for (int j = 0; j < NB; j++)
                if (b == sK[j]) atomicAdd(&subhist[j * 1024 + (k & 1023u)], 1u);
        }
    }
    grid_barrier(cnt, gen);

    // ---- C: resolve exact threshold keys (blocks 0..18)
    if (bid < NB) {
        int j = bid;
        u32 v[4];
        #pragma unroll
        for (int k = 0; k < 4; k++) v[k] = aload(&subhist[j * 1024 + tid * 4 + k]);
        u32 tsum = v[0] + v[1] + v[2] + v[3];
        sh[tid] = tsum; __syncthreads();
        for (int d = 1; d < TTHR; d <<= 1) {
            u32 x = (tid >= d) ? sh[tid - d] : 0u;
            __syncthreads(); sh[tid] += x; __syncthreads();
        }
        u32 run = sh[tid] - tsum;
        u32 off = aload(&meta[NB + j]);
        u32 bkt = aload(&meta[j]);
        #pragma unroll
        for (int k = 0; k < 4; k++) {
            if (run < off && off <= run + v[k])
                astore(&meta[2 * NB + j], KEY_MIN + (bkt << SUBSHIFT) + (u32)(tid * 4 + k));
            run += v[k];
        }
    }
    grid_barrier(cnt, gen);

    // ---- D: per-bin exact accumulation (ties at K_j go below, deterministic)
    if (tid < 4 * NBINS) { lc[tid / NBINS][tid % NBINS] = 0ull; la[tid / NBINS][tid % NBINS] = 0u; }
    if (tid < NB) sK[tid] = aload(&meta[2 * NB + tid]);
    __syncthreads();
    {
        int w = tid >> 6;
        int total4 = N >> 2;
        const uint4*  k4 = (const uint4*)keys;
        const uchar4* a4 = (const uchar4*)accb;
        for (int i = bid * TTHR + tid; i < total4; i += TBLK * TTHR) {
            uint4  kv = k4[i];
            uchar4 av = a4[i];
            u32 ks[4] = {kv.x, kv.y, kv.z, kv.w};
            u32 as[4] = {av.x, av.y, av.z, av.w};
            #pragma unroll
            for (int e = 0; e < 4; e++) {
                int bin = 0;
                #pragma unroll
                for (int j = 0; j < NB; j++) bin += (ks[e] > sK[j]) ? 1 : 0;
                float conf = __uint_as_float(ks[e]);
                u64 q = (u64)(conf * 4294967296.0f);   // exact: exponent shift
                atomicAdd(&lc[w][bin], (unsigned long long)q);
                atomicAdd(&la[w][bin], as[e]);
            }
        }
        for (int i = (total4 << 2) + bid * TTHR + tid; i < N; i += TBLK * TTHR) {
            u32 k = keys[i];
            int bin = 0;
            for (int j = 0; j < NB; j++) bin += (k > sK[j]) ? 1 : 0;
            u64 q = (u64)(__uint_as_float(k) * 4294967296.0f);
            atomicAdd(&lc[w][bin], (unsigned long long)q);
            atomicAdd(&la[w][bin], (u32)accb[i]);
        }
    }
    __syncthreads();
    if (tid < NBINS) {
        unsigned long long cq = lc[0][tid] + lc[1][tid] + lc[2][tid] + lc[3][tid];
        u32 ac = la[0][tid] + la[1][tid] + la[2][tid] + la[3][tid];
        if (cq) atomicAdd((unsigned long long*)&confQ[tid], cq);
        if (ac) atomicAdd(&accCnt[tid], ac);
    }
    grid_barrier(cnt, gen);

    // ---- E: final ECE
    if (bid == 0 && tid == 0) {
        double ece = 0.0;
        for (int b = 0; b < NBINS; b++) {
            u64 cq = aload64(&confQ[b]);
            u32 ac = aload(&accCnt[b]);
            double cm = (double)cq * (1.0 / 4294967296.0) / (double)W;
            double am = (double)ac / (double)W;
            ece += fabs(cm - am);
            out[1 + b] = (float)am;
        }
        out[0] = (float)(ece * (double)W / (double)N);
    }
}

extern "C" void kernel_launch(void* const* d_in, const int* in_sizes, int n_in,
                              void* d_out, int out_size, void* d_ws, size_t ws_size,
                              hipStream_t stream) {
    const float* logits = (const float*)d_in[0];
    const int*   labels = (const int*)d_in[1];
    int N = in_sizes[1];
    int C = in_sizes[0] / N;
    float* out = (float*)d_out;

    u8* ws = (u8*)d_ws;
    u32* keys = (u32*)ws;                                   // 4N
    u8*  accb = ws + (size_t)4 * N;                         // N
    size_t aux = ((size_t)5 * N + 255) & ~(size_t)255;
    // zero-initialized region:
    u64* confQ   = (u64*)(ws + aux);                        // 160
    u32* accCnt  = (u32*)(ws + aux + 160);                  // 80   -> 240
    u32* bar     = (u32*)(ws + aux + 240);                  // 16   -> 256
    u32* hist    = (u32*)(ws + aux + 256);                  // 229376 -> 229632
    u32* subhist = (u32*)(ws + aux + 229632);               // 77824  -> 307456
    u32* meta    = (u32*)(ws + aux + 307456);               // 3*NB*4 = 228 -> 307684
    size_t zbytes = 307684;
    // non-zeroed scratch (written before read):
    size_t poff = (aux + zbytes + 255) & ~(size_t)255;
    u32* partial    = (u32*)(ws + poff);                    // TBLK*4
    u32* chunk_excl = (u32*)(ws + poff + TBLK * 4);         // TBLK*4

    hipMemsetAsync(ws + aux, 0, zbytes, stream);

    u32 W = (u32)(N / NBINS);

    if (C == 100) {
        int blocks1 = (N + 15) / 16;  // 4 waves x 4 row-groups of 16 lanes
        k1_conf100<<<blocks1, 256, 0, stream>>>(logits, labels, keys, accb, hist, N);
    } else {
        int blocks1 = (N + 255) / 256;
        k1_generic<<<blocks1, 256, 0, stream>>>(logits, labels, keys, accb, hist, N, C);
    }
    tail_kernel<<<TBLK, TTHR, 0, stream>>>(keys, accb, hist, subhist, meta,
                                           partial, chunk_excl, confQ, accCnt,
                                           bar, out, N, W);
}

// Round 4
// 190.473 us; speedup vs baseline: 6.6172x; 6.6172x over previous
//
#include <hip/hip_runtime.h>
#include <stdint.h>

typedef uint32_t u32;
typedef uint64_t u64;
typedef uint8_t  u8;

#define KEY_MIN   0x3C000000u   /* conf = max softmax >= 1/C = 0.01 > 2^-7 */
#define SUBSHIFT  10
#define NBUCK     57344         /* (0x3F800000 - 0x3C000000) >> 10 */
#define NBINS     20
#define NB        19

__device__ __forceinline__ u32 bucket_of(u32 key) {
    if (key < KEY_MIN) return 0u;
    u32 b = (key - KEY_MIN) >> SUBSHIFT;
    return b < (u32)NBUCK ? b : (u32)(NBUCK - 1);
}

// ---------------- K1 (C==100): 16 lanes per row, coalesced --------------------
__global__ __launch_bounds__(256) void k1_conf100(
        const float* __restrict__ logits, const int* __restrict__ labels,
        u32* __restrict__ keys, u8* __restrict__ accb, u32* __restrict__ hist,
        int N) {
    const int C4 = 25;
    int lane = threadIdx.x & 63;
    int wid  = (blockIdx.x * (blockDim.x >> 6)) + (threadIdx.x >> 6);
    int g    = lane >> 4;
    int sub  = lane & 15;
    int r    = wid * 4 + g;
    if (r >= N) return;

    const float4* row4 = (const float4*)(logits + (size_t)r * 100);
    float4 v0 = row4[sub];
    float4 v1;
    bool has2 = (sub + 16) < C4;
    if (has2) v1 = row4[sub + 16];
    else      v1 = make_float4(-3.4e38f, -3.4e38f, -3.4e38f, -3.4e38f);

    float m = v0.x; int am = 4 * sub;
    if (v0.y > m) { m = v0.y; am = 4 * sub + 1; }
    if (v0.z > m) { m = v0.z; am = 4 * sub + 2; }
    if (v0.w > m) { m = v0.w; am = 4 * sub + 3; }
    int b2 = 64 + 4 * sub;
    if (v1.x > m) { m = v1.x; am = b2; }
    if (v1.y > m) { m = v1.y; am = b2 + 1; }
    if (v1.z > m) { m = v1.z; am = b2 + 2; }
    if (v1.w > m) { m = v1.w; am = b2 + 3; }

    #pragma unroll
    for (int off = 8; off >= 1; off >>= 1) {
        float om = __shfl_xor(m, off);
        int   oa = __shfl_xor(am, off);
        if (om > m || (om == m && oa < am)) { m = om; am = oa; }
    }

    float s = __expf(v0.x - m) + __expf(v0.y - m) + __expf(v0.z - m) + __expf(v0.w - m);
    if (has2) s += __expf(v1.x - m) + __expf(v1.y - m) + __expf(v1.z - m) + __expf(v1.w - m);
    #pragma unroll
    for (int off = 8; off >= 1; off >>= 1) s += __shfl_xor(s, off);

    if (sub == 0) {
        float conf = 1.0f / s;
        u32 key = __float_as_uint(conf);
        keys[r] = key;
        accb[r] = (labels[r] == am) ? (u8)1 : (u8)0;
        atomicAdd(&hist[bucket_of(key)], 1u);
    }
}

// ---------------- K1 generic fallback -----------------------------------------
__global__ __launch_bounds__(256) void k1_generic(
        const float* __restrict__ logits, const int* __restrict__ labels,
        u32* __restrict__ keys, u8* __restrict__ accb, u32* __restrict__ hist,
        int N, int C) {
    int i = blockIdx.x * blockDim.x + threadIdx.x;
    if (i >= N) return;
    const float* row = logits + (size_t)i * (size_t)C;
    float m = -3.4e38f, s = 0.f;
    int am = 0;
    for (int c = 0; c < C; c++) {
        float v = row[c];
        float nm = fmaxf(m, v); am = (v > m) ? c : am;
        s = s * __expf(m - nm) + __expf(v - nm); m = nm;
    }
    float conf = 1.0f / s;
    u32 key = __float_as_uint(conf);
    keys[i] = key;
    accb[i] = (labels[i] == am) ? (u8)1 : (u8)0;
    atomicAdd(&hist[bucket_of(key)], 1u);
}

// meta: 0..18 bBucket | 19..37 bOff | 38..56 Kkey
// ---------------- K2: scan histogram, find boundary buckets (1 block) ---------
__global__ void k2_scan(const u32* __restrict__ hist, u32* __restrict__ meta,
                        u32 W) {
    __shared__ u32 sp[1024];
    int t = threadIdx.x;
    const int PER = NBUCK / 1024;  // 56
    u32 s = 0;
    for (int k = 0; k < PER; k++) s += hist[t * PER + k];
    sp[t] = s; __syncthreads();
    for (int d = 1; d < 1024; d <<= 1) {
        u32 v = (t >= d) ? sp[t - d] : 0u;
        __syncthreads();
        sp[t] += v;
        __syncthreads();
    }
    u32 cum = sp[t] - s;  // exclusive prefix over this thread's 56 buckets
    for (int k = 0; k < PER; k++) {
        u32 c = hist[t * PER + k];
        if (c) {
            for (int j = 0; j < NB; j++) {
                u32 r = (u32)(j + 1) * W;
                if (cum < r && r <= cum + c) {
                    meta[j] = (u32)(t * PER + k);   // boundary bucket
                    meta[NB + j] = r - cum;         // samples of bucket below boundary
                }
            }
        }
        cum += c;
    }
}

// ---------------- K3: sub-histogram (low 10 bits) of boundary buckets ---------
__global__ __launch_bounds__(256) void k3_subhist(
        const u32* __restrict__ keys, const u32* __restrict__ meta,
        u32* __restrict__ subhist, int N) {
    __shared__ u32 sB[NB];
    if (threadIdx.x < NB) sB[threadIdx.x] = meta[threadIdx.x];
    __syncthreads();
    int total4 = N >> 2;
    const uint4* k4 = (const uint4*)keys;
    for (int i = blockIdx.x * blockDim.x + threadIdx.x; i < total4;
         i += gridDim.x * blockDim.x) {
        uint4 kv = k4[i];
        u32 ks[4] = {kv.x, kv.y, kv.z, kv.w};
        #pragma unroll
        for (int e = 0; e < 4; e++) {
            u32 b = bucket_of(ks[e]);
            #pragma unroll
            for (int j = 0; j < NB; j++)
                if (b == sB[j]) atomicAdd(&subhist[j * 1024 + (ks[e] & 1023u)], 1u);
        }
    }
    for (int i = (total4 << 2) + blockIdx.x * blockDim.x + threadIdx.x; i < N;
         i += gridDim.x * blockDim.x) {
        u32 k = keys[i];
        u32 b = bucket_of(k);
        for (int j = 0; j < NB; j++)
            if (b == sB[j]) atomicAdd(&subhist[j * 1024 + (k & 1023u)], 1u);
    }
}

// ---------------- K4: resolve exact threshold keys (19 blocks x 256) ----------
__global__ void k4_resolve(const u32* __restrict__ subhist, u32* __restrict__ meta) {
    int j = blockIdx.x;
    int t = threadIdx.x;
    __shared__ u32 sh[256];
    u32 v[4];
    #pragma unroll
    for (int k = 0; k < 4; k++) v[k] = subhist[j * 1024 + t * 4 + k];
    u32 tsum = v[0] + v[1] + v[2] + v[3];
    sh[t] = tsum; __syncthreads();
    for (int d = 1; d < 256; d <<= 1) {
        u32 x = (t >= d) ? sh[t - d] : 0u;
        __syncthreads(); sh[t] += x; __syncthreads();
    }
    u32 run = sh[t] - tsum;
    u32 off = meta[NB + j];
    u32 bkt = meta[j];
    #pragma unroll
    for (int k = 0; k < 4; k++) {
        if (run < off && off <= run + v[k])
            meta[2 * NB + j] = KEY_MIN + (bkt << SUBSHIFT) + (u32)(t * 4 + k);
        run += v[k];
    }
}

// ---------------- K7: per-bin exact accumulation (per-wave LDS bins) ----------
__global__ __launch_bounds__(256) void k7_accum(
        const u32* __restrict__ keys, const u8* __restrict__ accb,
        const u32* __restrict__ meta, u64* __restrict__ confQ,
        u32* __restrict__ accCnt, int N) {
    __shared__ unsigned long long lc[4][NBINS];
    __shared__ u32 la[4][NBINS];
    __shared__ u32 sK[NB];
    int t = threadIdx.x;
    int w = t >> 6;
    if (t < 4 * NBINS) { lc[t / NBINS][t % NBINS] = 0ull; la[t / NBINS][t % NBINS] = 0u; }
    if (t < NB) sK[t] = meta[2 * NB + t];
    __syncthreads();
    int total4 = N >> 2;
    const uint4*  k4 = (const uint4*)keys;
    const uchar4* a4 = (const uchar4*)accb;
    for (int i = blockIdx.x * blockDim.x + t; i < total4; i += gridDim.x * blockDim.x) {
        uint4  kv = k4[i];
        uchar4 av = a4[i];
        u32 ks[4] = {kv.x, kv.y, kv.z, kv.w};
        u32 as[4] = {av.x, av.y, av.z, av.w};
        #pragma unroll
        for (int e = 0; e < 4; e++) {
            int bin = 0;
            #pragma unroll
            for (int j = 0; j < NB; j++) bin += (ks[e] > sK[j]) ? 1 : 0;
            float conf = __uint_as_float(ks[e]);
            u64 q = (u64)(conf * 4294967296.0f);   // exact: exponent shift
            atomicAdd(&lc[w][bin], (unsigned long long)q);
            atomicAdd(&la[w][bin], as[e]);
        }
    }
    for (int i = (total4 << 2) + blockIdx.x * blockDim.x + t; i < N;
         i += gridDim.x * blockDim.x) {
        u32 k = keys[i];
        int bin = 0;
        for (int j = 0; j < NB; j++) bin += (k > sK[j]) ? 1 : 0;
        u64 q = (u64)(__uint_as_float(k) * 4294967296.0f);
        atomicAdd(&lc[w][bin], (unsigned long long)q);
        atomicAdd(&la[w][bin], (u32)accb[i]);
    }
    __syncthreads();
    if (t < NBINS) {
        unsigned long long cq = lc[0][t] + lc[1][t] + lc[2][t] + lc[3][t];
        u32 ac = la[0][t] + la[1][t] + la[2][t] + la[3][t];
        if (cq) atomicAdd((unsigned long long*)&confQ[t], cq);
        if (ac) atomicAdd(&accCnt[t], ac);
    }
}

// ---------------- K8: final ECE -----------------------------------------------
__global__ void k8_final(const u64* __restrict__ confQ, const u32* __restrict__ accCnt,
                         float* __restrict__ out, int W, int N) {
    if (threadIdx.x == 0 && blockIdx.x == 0) {
        double ece = 0.0;
        for (int b = 0; b < NBINS; b++) {
            double cm = (double)confQ[b] * (1.0 / 4294967296.0) / (double)W;
            double am = (double)accCnt[b] / (double)W;
            ece += fabs(cm - am);
            out[1 + b] = (float)am;
        }
        out[0] = (float)(ece * (double)W / (double)N);
    }
}

extern "C" void kernel_launch(void* const* d_in, const int* in_sizes, int n_in,
                              void* d_out, int out_size, void* d_ws, size_t ws_size,
                              hipStream_t stream) {
    const float* logits = (const float*)d_in[0];
    const int*   labels = (const int*)d_in[1];
    int N = in_sizes[1];
    int C = in_sizes[0] / N;
    float* out = (float*)d_out;

    u8* ws = (u8*)d_ws;
    u32* keys = (u32*)ws;                                   // 4N
    u8*  accb = ws + (size_t)4 * N;                         // N
    size_t aux = ((size_t)5 * N + 255) & ~(size_t)255;
    // zero-initialized region:
    u64* confQ   = (u64*)(ws + aux);                        // 160
    u32* accCnt  = (u32*)(ws + aux + 160);                  // 80   -> 240 (+16 pad)
    u32* hist    = (u32*)(ws + aux + 256);                  // 229376 -> 229632
    u32* subhist = (u32*)(ws + aux + 229632);               // 77824  -> 307456
    u32* meta    = (u32*)(ws + aux + 307456);               // 3*NB*4 = 228
    size_t zbytes = 307456 + 228;

    hipMemsetAsync(ws + aux, 0, zbytes, stream);

    u32 W = (u32)(N / NBINS);

    if (C == 100) {
        int blocks1 = (N + 15) / 16;  // 16 rows/block: 4 waves x 4 row-groups
        k1_conf100<<<blocks1, 256, 0, stream>>>(logits, labels, keys, accb, hist, N);
    } else {
        int blocks1 = (N + 255) / 256;
        k1_generic<<<blocks1, 256, 0, stream>>>(logits, labels, keys, accb, hist, N, C);
    }
    k2_scan   <<<1, 1024, 0, stream>>>(hist, meta, W);
    k3_subhist<<<1024, 256, 0, stream>>>(keys, meta, subhist, N);
    k4_resolve<<<NB, 256, 0, stream>>>(subhist, meta);
    k7_accum  <<<1024, 256, 0, stream>>>(keys, accb, meta, confQ, accCnt, N);
    k8_final  <<<1, 64, 0, stream>>>(confQ, accCnt, out, (int)W, N);
}